// Round 2
// baseline (199.260 us; speedup 1.0000x reference)
//
#include <hip/hip_runtime.h>
#include <hip/hip_bf16.h>

// CTRNN fused kernel for MI355X (gfx950).
// B=8192, D=512, N=512, K=D+N=1024, 6 unfolds, dt=0.1, tau=1.
// state' = 0.9*state + 0.1*tanh(inputs@W_in + state@W_rec + bias)
//
// R2 change vs R1: W is pre-packed into MFMA-fragment-major order (WTf) so
// every B-fragment load is one contiguous, coalesced 1KB wave transaction
// (R1's layout had a 2KB lane stride -> 16-way cache-line scatter + L2
// channel aliasing -> latency-bound at 8.5% MfmaUtil). Also: depth-1 group
// software pipeline on B loads, and acc is pre-initialized with proj.

#define BB 8192
#define DD 512
#define NN 512
#define KK 1024
#define BM 32
#define NTHREADS 512
#define NUNFOLD 6

using short8 = __attribute__((ext_vector_type(8))) short;
using f32x4  = __attribute__((ext_vector_type(4))) float;

__device__ __forceinline__ unsigned short f2bf(float f) {
    // round-to-nearest-even f32 -> bf16 (finite inputs only)
    unsigned int u = __float_as_uint(f);
    u += 0x7fffu + ((u >> 16) & 1u);
    return (unsigned short)(u >> 16);
}

// Pack W (f32, [k=1024][n=512] row-major) into bf16 fragment-major layout:
// chunk index = (ct*32 + ks)*64 + lane, each chunk = 8 bf16 = 16B, where
//   n = ct*16 + (lane&15),  k = ks*32 + (lane>>4)*8 + e   (e = 0..7)
// A wave loading fragment (ct, ks) reads one contiguous 1KB block.
__global__ void w_to_frag(const float* __restrict__ W,
                          unsigned short* __restrict__ WTf) {
    int gid  = blockIdx.x * blockDim.x + threadIdx.x;  // 0..65535
    int lane = gid & 63;
    int frag = gid >> 6;        // ct*32 + ks
    int ks   = frag & 31;
    int ct   = frag >> 5;
    int n  = ct * 16 + (lane & 15);
    int k0 = ks * 32 + (lane >> 4) * 8;
    unsigned short v[8];
#pragma unroll
    for (int e = 0; e < 8; ++e)
        v[e] = f2bf(W[(size_t)(k0 + e) * NN + n]);
    *reinterpret_cast<short8*>(WTf + (size_t)gid * 8) =
        *reinterpret_cast<const short8*>(v);
}

__global__ __launch_bounds__(NTHREADS, 2)
void ctrnn_fused(const float* __restrict__ inputs,
                 const float* __restrict__ state,
                 const float* __restrict__ bias,
                 const unsigned short* __restrict__ WTf,
                 float* __restrict__ out) {
    // bf16 A-tile, [r][c], XOR-swizzled byte addr
    __shared__ __align__(16) char Alds[BM * DD * 2];  // 32 KB

    const int tid  = threadIdx.x;
    const int lane = tid & 63;
    const int wv   = tid >> 6;        // wave 0..7, owns cols [wv*64, wv*64+64)
    const int row0 = blockIdx.x * BM;
    const int l15  = lane & 15;
    const int l4   = lane >> 4;       // 0..3
    const int lane_k = l4 * 8;

    const short8* WTf8 = reinterpret_cast<const short8*>(WTf);
    // b(nt, ksg) = Bw[(nt*32 + ksg)*64]   (ksg: 0..15 = W_in, 16..31 = W_rec)
    const short8* Bw = WTf8 + (size_t)(wv * 4) * 32 * 64 + lane;

    auto lda = [&](int mt, int k) -> short8 {
        int r = mt * 16 + l15;
        int byte = (r * 1024 + k * 2) ^ ((r & 7) << 4);
        return *reinterpret_cast<const short8*>(&Alds[byte]);
    };
    auto stage = [&](const float* __restrict__ src) {
        const float4* s4 = reinterpret_cast<const float4*>(src);
#pragma unroll
        for (int i = 0; i < 8; ++i) {
            int q  = tid + i * NTHREADS;  // 0..4095 = r*128 + c4
            int r  = q >> 7;
            int c4 = q & 127;
            float4 v = s4[q];
            uint2 p;
            p.x = (unsigned int)f2bf(v.x) | ((unsigned int)f2bf(v.y) << 16);
            p.y = (unsigned int)f2bf(v.z) | ((unsigned int)f2bf(v.w) << 16);
            int byte = (r * 1024 + c4 * 8) ^ ((r & 7) << 4);
            *reinterpret_cast<uint2*>(&Alds[byte]) = p;
        }
    };

    f32x4 acc[2][4];
    short8 bb[2][4][4];  // [group parity][kk][nt], depth-1 pipeline

    // One K=512 GEMM pass; acc must be pre-initialized by caller.
    auto gemm = [&](int ksbase) {
#pragma unroll
        for (int kk = 0; kk < 4; ++kk)
#pragma unroll
            for (int nt = 0; nt < 4; ++nt)
                bb[0][kk][nt] = Bw[(size_t)(nt * 32 + ksbase + kk) * 64];
#pragma unroll
        for (int g = 0; g < 4; ++g) {
            if (g < 3) {
#pragma unroll
                for (int kk = 0; kk < 4; ++kk)
#pragma unroll
                    for (int nt = 0; nt < 4; ++nt)
                        bb[(g + 1) & 1][kk][nt] =
                            Bw[(size_t)(nt * 32 + ksbase + (g + 1) * 4 + kk) * 64];
            }
#pragma unroll
            for (int kk = 0; kk < 4; ++kk) {
                int k = (g * 4 + kk) * 32 + lane_k;
                short8 a0 = lda(0, k);
                short8 a1 = lda(1, k);
#pragma unroll
                for (int nt = 0; nt < 4; ++nt) {
                    acc[0][nt] = __builtin_amdgcn_mfma_f32_16x16x32_bf16(
                        a0, bb[g & 1][kk][nt], acc[0][nt], 0, 0, 0);
                    acc[1][nt] = __builtin_amdgcn_mfma_f32_16x16x32_bf16(
                        a1, bb[g & 1][kk][nt], acc[1][nt], 0, 0, 0);
                }
            }
        }
    };

    // ---------------- phase 1: proj = inputs @ W_in + bias ----------------
    stage(inputs + (size_t)row0 * DD);
    __syncthreads();

#pragma unroll
    for (int mt = 0; mt < 2; ++mt)
#pragma unroll
        for (int nt = 0; nt < 4; ++nt)
            acc[mt][nt] = f32x4{0.f, 0.f, 0.f, 0.f};
    gemm(0);

    f32x4 proj[2][4];
#pragma unroll
    for (int nt = 0; nt < 4; ++nt) {
        float bv = bias[wv * 64 + nt * 16 + l15];
#pragma unroll
        for (int mt = 0; mt < 2; ++mt)
#pragma unroll
            for (int j = 0; j < 4; ++j)
                proj[mt][nt][j] = acc[mt][nt][j] + bv;
    }

    // ---------------- phase 2: load state (LDS bf16 + f32 regs) ----------------
    __syncthreads();  // proj GEMM LDS reads done, safe to overwrite
    stage(state + (size_t)row0 * NN);

    f32x4 sreg[2][4];  // f32 master state at C-layout positions
#pragma unroll
    for (int mt = 0; mt < 2; ++mt)
#pragma unroll
        for (int nt = 0; nt < 4; ++nt)
#pragma unroll
            for (int j = 0; j < 4; ++j)
                sreg[mt][nt][j] =
                    state[(size_t)(row0 + mt * 16 + l4 * 4 + j) * NN +
                          (wv * 64 + nt * 16 + l15)];
    __syncthreads();

    // ---------------- phase 3: 6 unfolds ----------------
    for (int u = 0; u < NUNFOLD; ++u) {
#pragma unroll
        for (int mt = 0; mt < 2; ++mt)
#pragma unroll
            for (int nt = 0; nt < 4; ++nt)
                acc[mt][nt] = proj[mt][nt];  // pre-init with inputs@W_in + b
        gemm(16);
        __syncthreads();  // all LDS reads of old state done

#pragma unroll
        for (int mt = 0; mt < 2; ++mt)
#pragma unroll
            for (int nt = 0; nt < 4; ++nt)
#pragma unroll
                for (int j = 0; j < 4; ++j) {
                    float x = acc[mt][nt][j];
                    float t = 1.f - 2.f / (__expf(2.f * x) + 1.f);  // tanh(x)
                    float s = sreg[mt][nt][j] * 0.9f + 0.1f * t;
                    sreg[mt][nt][j] = s;
                    int r = mt * 16 + l4 * 4 + j;
                    int c = wv * 64 + nt * 16 + l15;
                    int byte = (r * 1024 + c * 2) ^ ((r & 7) << 4);
                    *reinterpret_cast<unsigned short*>(&Alds[byte]) = f2bf(s);
                }
        __syncthreads();  // new state visible before next unfold's reads
    }

    // ---------------- epilogue: out = (state, state) ----------------
#pragma unroll
    for (int mt = 0; mt < 2; ++mt)
#pragma unroll
        for (int nt = 0; nt < 4; ++nt)
#pragma unroll
            for (int j = 0; j < 4; ++j) {
                size_t r = (size_t)(row0 + mt * 16 + l4 * 4 + j);
                int c = wv * 64 + nt * 16 + l15;
                float s = sreg[mt][nt][j];
                out[r * NN + c] = s;
                out[(size_t)BB * NN + r * NN + c] = s;
            }
}

extern "C" void kernel_launch(void* const* d_in, const int* in_sizes, int n_in,
                              void* d_out, int out_size, void* d_ws, size_t ws_size,
                              hipStream_t stream) {
    const float* inputs = (const float*)d_in[0];
    const float* state  = (const float*)d_in[1];
    const float* W      = (const float*)d_in[2];   // (1024, 512) row-major
    const float* bias   = (const float*)d_in[3];   // (512,)
    float* out = (float*)d_out;                    // 2 * 8192*512 f32
    unsigned short* WTf = (unsigned short*)d_ws;   // bf16 fragment-major, 1 MB

    w_to_frag<<<(KK / 32) * (NN / 16) * 64 / 512, 512, 0, stream>>>(W, WTf);
    ctrnn_fused<<<BB / BM, NTHREADS, 0, stream>>>(inputs, state, bias, WTf, out);
}

// Round 3
// 94.571 us; speedup vs baseline: 2.1070x; 2.1070x over previous
//
#include <hip/hip_runtime.h>
#include <hip/hip_bf16.h>

// CTRNN fused kernel for MI355X (gfx950).
// B=8192, D=512, N=512, K=D+N=1024, 6 unfolds, dt=0.1, tau=1.
// state' = 0.9*state + 0.1*tanh(inputs@W_in + state@W_rec + bias)
//
// R3 = R1's register structure (no manual prefetch arrays -> no spills)
//    + R2's fragment-major W layout (every B-load = one contiguous 1KB
//      wave transaction; R1's 2KB-lane-stride loads aliased to ~2 L2
//      channels and made the kernel latency-bound at 8.5% MfmaUtil).
// R2's regression was register spilling (bb[2][4][4] = 128 VGPRs ->
// WRITE_SIZE 33->143MB scratch traffic), not the layout.

#define BB 8192
#define DD 512
#define NN 512
#define KK 1024
#define BM 32
#define NTHREADS 512
#define NUNFOLD 6

using short8 = __attribute__((ext_vector_type(8))) short;
using f32x4  = __attribute__((ext_vector_type(4))) float;

__device__ __forceinline__ unsigned short f2bf(float f) {
    // round-to-nearest-even f32 -> bf16 (finite inputs only)
    unsigned int u = __float_as_uint(f);
    u += 0x7fffu + ((u >> 16) & 1u);
    return (unsigned short)(u >> 16);
}

// Pack W (f32, [k=1024][n=512] row-major) into bf16 fragment-major layout:
// chunk index = (ct*32 + ks)*64 + lane, each chunk = 8 bf16 = 16B, where
//   n = ct*16 + (lane&15),  k = ks*32 + (lane>>4)*8 + e   (e = 0..7)
// A wave loading fragment (ct, ks) reads one contiguous 1KB block.
__global__ void w_to_frag(const float* __restrict__ W,
                          unsigned short* __restrict__ WTf) {
    int gid  = blockIdx.x * blockDim.x + threadIdx.x;  // 0..65535
    int lane = gid & 63;
    int frag = gid >> 6;        // ct*32 + ks
    int ks   = frag & 31;
    int ct   = frag >> 5;
    int n  = ct * 16 + (lane & 15);
    int k0 = ks * 32 + (lane >> 4) * 8;
    unsigned short v[8];
#pragma unroll
    for (int e = 0; e < 8; ++e)
        v[e] = f2bf(W[(size_t)(k0 + e) * NN + n]);
    *reinterpret_cast<short8*>(WTf + (size_t)gid * 8) =
        *reinterpret_cast<const short8*>(v);
}

__global__ __launch_bounds__(NTHREADS, 2)
void ctrnn_fused(const float* __restrict__ inputs,
                 const float* __restrict__ state,
                 const float* __restrict__ bias,
                 const unsigned short* __restrict__ WTf,
                 float* __restrict__ out) {
    // bf16 A-tile, [r][c], XOR-swizzled byte addr
    __shared__ __align__(16) char Alds[BM * DD * 2];  // 32 KB

    const int tid  = threadIdx.x;
    const int lane = tid & 63;
    const int wv   = tid >> 6;        // wave 0..7, owns cols [wv*64, wv*64+64)
    const int row0 = blockIdx.x * BM;
    const int l15  = lane & 15;
    const int l4   = lane >> 4;       // 0..3
    const int lane_k = l4 * 8;

    const short8* WTf8 = reinterpret_cast<const short8*>(WTf);
    // b(nt, ksg) = Bw[(nt*32 + ksg)*64]   (ksg: 0..15 = W_in, 16..31 = W_rec)
    const short8* Bw = WTf8 + (size_t)(wv * 4) * 32 * 64 + lane;

    auto lda = [&](int mt, int k) -> short8 {
        int r = mt * 16 + l15;
        int byte = (r * 1024 + k * 2) ^ ((r & 7) << 4);
        return *reinterpret_cast<const short8*>(&Alds[byte]);
    };
    auto stage = [&](const float* __restrict__ src) {
        const float4* s4 = reinterpret_cast<const float4*>(src);
#pragma unroll
        for (int i = 0; i < 8; ++i) {
            int q  = tid + i * NTHREADS;  // 0..4095 = r*128 + c4
            int r  = q >> 7;
            int c4 = q & 127;
            float4 v = s4[q];
            uint2 p;
            p.x = (unsigned int)f2bf(v.x) | ((unsigned int)f2bf(v.y) << 16);
            p.y = (unsigned int)f2bf(v.z) | ((unsigned int)f2bf(v.w) << 16);
            int byte = (r * 1024 + c4 * 8) ^ ((r & 7) << 4);
            *reinterpret_cast<uint2*>(&Alds[byte]) = p;
        }
    };

    f32x4 acc[2][4];

    // One K=512 GEMM pass; acc must be pre-initialized by caller.
    // B-loads are contiguous 1KB wave transactions (fragment-major layout);
    // unroll-4 gives the scheduler 16 loads + 8 ds_reads per group to hoist.
    auto gemm = [&](int ksbase) {
#pragma unroll 4
        for (int ks = 0; ks < 16; ++ks) {
            short8 b[4];
#pragma unroll
            for (int nt = 0; nt < 4; ++nt)
                b[nt] = Bw[(size_t)(nt * 32 + ksbase + ks) * 64];
            int k = ks * 32 + lane_k;
            short8 a0 = lda(0, k);
            short8 a1 = lda(1, k);
#pragma unroll
            for (int nt = 0; nt < 4; ++nt) {
                acc[0][nt] = __builtin_amdgcn_mfma_f32_16x16x32_bf16(
                    a0, b[nt], acc[0][nt], 0, 0, 0);
                acc[1][nt] = __builtin_amdgcn_mfma_f32_16x16x32_bf16(
                    a1, b[nt], acc[1][nt], 0, 0, 0);
            }
        }
    };

    // ---------------- phase 1: proj = inputs @ W_in + bias ----------------
    stage(inputs + (size_t)row0 * DD);

    // f32 master state at C-layout positions; issue loads early so they
    // overlap the proj GEMM (first use is after gemm(0)).
    f32x4 sreg[2][4];
#pragma unroll
    for (int mt = 0; mt < 2; ++mt)
#pragma unroll
        for (int nt = 0; nt < 4; ++nt)
#pragma unroll
            for (int j = 0; j < 4; ++j)
                sreg[mt][nt][j] =
                    state[(size_t)(row0 + mt * 16 + l4 * 4 + j) * NN +
                          (wv * 64 + nt * 16 + l15)];

    __syncthreads();

#pragma unroll
    for (int mt = 0; mt < 2; ++mt)
#pragma unroll
        for (int nt = 0; nt < 4; ++nt)
            acc[mt][nt] = f32x4{0.f, 0.f, 0.f, 0.f};
    gemm(0);

    f32x4 proj[2][4];
#pragma unroll
    for (int nt = 0; nt < 4; ++nt) {
        float bv = bias[wv * 64 + nt * 16 + l15];
#pragma unroll
        for (int mt = 0; mt < 2; ++mt)
#pragma unroll
            for (int j = 0; j < 4; ++j)
                proj[mt][nt][j] = acc[mt][nt][j] + bv;
    }

    // ---------------- phase 2: stage state into LDS as bf16 ----------------
    __syncthreads();  // proj GEMM LDS reads done, safe to overwrite
    stage(state + (size_t)row0 * NN);
    __syncthreads();

    // ---------------- phase 3: 6 unfolds ----------------
    for (int u = 0; u < NUNFOLD; ++u) {
#pragma unroll
        for (int mt = 0; mt < 2; ++mt)
#pragma unroll
            for (int nt = 0; nt < 4; ++nt)
                acc[mt][nt] = proj[mt][nt];  // pre-init with inputs@W_in + b
        gemm(16);
        __syncthreads();  // all LDS reads of old state done

#pragma unroll
        for (int mt = 0; mt < 2; ++mt)
#pragma unroll
            for (int nt = 0; nt < 4; ++nt)
#pragma unroll
                for (int j = 0; j < 4; ++j) {
                    float x = acc[mt][nt][j];
                    float t = 1.f - 2.f / (__expf(2.f * x) + 1.f);  // tanh(x)
                    float s = sreg[mt][nt][j] * 0.9f + 0.1f * t;
                    sreg[mt][nt][j] = s;
                    int r = mt * 16 + l4 * 4 + j;
                    int c = wv * 64 + nt * 16 + l15;
                    int byte = (r * 1024 + c * 2) ^ ((r & 7) << 4);
                    *reinterpret_cast<unsigned short*>(&Alds[byte]) = f2bf(s);
                }
        __syncthreads();  // new state visible before next unfold's reads
    }

    // ---------------- epilogue: out = (state, state) ----------------
#pragma unroll
    for (int mt = 0; mt < 2; ++mt)
#pragma unroll
        for (int nt = 0; nt < 4; ++nt)
#pragma unroll
            for (int j = 0; j < 4; ++j) {
                size_t r = (size_t)(row0 + mt * 16 + l4 * 4 + j);
                int c = wv * 64 + nt * 16 + l15;
                float s = sreg[mt][nt][j];
                out[r * NN + c] = s;
                out[(size_t)BB * NN + r * NN + c] = s;
            }
}

extern "C" void kernel_launch(void* const* d_in, const int* in_sizes, int n_in,
                              void* d_out, int out_size, void* d_ws, size_t ws_size,
                              hipStream_t stream) {
    const float* inputs = (const float*)d_in[0];
    const float* state  = (const float*)d_in[1];
    const float* W      = (const float*)d_in[2];   // (1024, 512) row-major
    const float* bias   = (const float*)d_in[3];   // (512,)
    float* out = (float*)d_out;                    // 2 * 8192*512 f32
    unsigned short* WTf = (unsigned short*)d_ws;   // bf16 fragment-major, 1 MB

    w_to_frag<<<(KK / 32) * (NN / 16) * 64 / 512, 512, 0, stream>>>(W, WTf);
    ctrnn_fused<<<BB / BM, NTHREADS, 0, stream>>>(inputs, state, bias, WTf, out);
}